// Round 1
// baseline (872.524 us; speedup 1.0000x reference)
//
#include <hip/hip_runtime.h>
#include <cstdint>

#define DD     1024
#define NINNER 4096
#define NTOK   32768   // B*T = 8*4096
#define MROWS  8192    // tokens per expert

typedef unsigned short u16;
typedef __bf16 bf16x8 __attribute__((ext_vector_type(8)));
typedef float  f32x4  __attribute__((ext_vector_type(4)));

// fp32 -> bf16 round-to-nearest-even
__device__ __forceinline__ u16 f2bf(float f) {
    union { float f; uint32_t u; } a; a.f = f;
    uint32_t r = a.u + 0x7fffu + ((a.u >> 16) & 1u);
    return (u16)(r >> 16);
}

// async global->LDS, 16B per lane; LDS dest = wave-uniform base + lane*16
__device__ __forceinline__ void async16(const void* g, void* l) {
    __builtin_amdgcn_global_load_lds(
        (const __attribute__((address_space(1))) void*)g,
        (__attribute__((address_space(3))) void*)l,
        16, 0, 0);
}

// ---------------- weight cast: fp32 -> bf16 ----------------
__global__ __launch_bounds__(256) void cast_w(
    const float* __restrict__ w1, const float* __restrict__ w2,
    u16* __restrict__ w1b, u16* __restrict__ w2b)
{
    int idx = blockIdx.x * 256 + threadIdx.x;     // float4 index
    const int n1 = (NINNER * DD) / 4;             // 1M float4 in l1_w
    float4 v; ushort4 o;
    if (idx < n1) {
        v = ((const float4*)w1)[idx];
        o.x = f2bf(v.x); o.y = f2bf(v.y); o.z = f2bf(v.z); o.w = f2bf(v.w);
        ((ushort4*)w1b)[idx] = o;
    } else {
        int j = idx - n1;
        v = ((const float4*)w2)[j];
        o.x = f2bf(v.x); o.y = f2bf(v.y); o.z = f2bf(v.z); o.w = f2bf(v.w);
        ((ushort4*)w2b)[j] = o;
    }
}

// ---------------- LayerNorm -> bf16 h, plus FULL out init ----------------
__global__ __launch_bounds__(256) void ln_kernel(
    const float* __restrict__ x, const float* __restrict__ nw,
    const float* __restrict__ nb, const float* __restrict__ l2b,
    const float* __restrict__ rp, const float* __restrict__ alphap,
    u16* __restrict__ h, float* __restrict__ out)
{
    const int row = blockIdx.x;          // 0..32767 global token
    const int tid = threadIdx.x;
    const float4 v = ((const float4*)(x + (size_t)row * DD))[tid];
    float s  = v.x + v.y + v.z + v.w;
    float s2 = v.x*v.x + v.y*v.y + v.z*v.z + v.w*v.w;
#pragma unroll
    for (int o = 32; o > 0; o >>= 1) {
        s  += __shfl_down(s,  o, 64);
        s2 += __shfl_down(s2, o, 64);
    }
    __shared__ float as1[4], as2[4];
    if ((tid & 63) == 0) { as1[tid >> 6] = s; as2[tid >> 6] = s2; }
    __syncthreads();
    const float S  = as1[0] + as1[1] + as1[2] + as1[3];
    const float S2 = as2[0] + as2[1] + as2[2] + as2[3];
    const float mu  = S  * (1.0f / 1024.0f);
    const float var = S2 * (1.0f / 1024.0f) - mu * mu;
    const float rs  = rsqrtf(var + 1e-5f);
    const float4 w4 = ((const float4*)nw)[tid];
    const float4 b4 = ((const float4*)nb)[tid];
    ushort4 hv;
    hv.x = f2bf((v.x - mu) * rs * w4.x + b4.x);
    hv.y = f2bf((v.y - mu) * rs * w4.y + b4.y);
    hv.z = f2bf((v.z - mu) * rs * w4.z + b4.z);
    hv.w = f2bf((v.w - mu) * rs * w4.w + b4.w);
    ((ushort4*)(h + (size_t)row * DD))[tid] = hv;

    const int e = (row >> 10) & 3;
    const int m = DD >> e;
    float4 o4;
    if (tid * 4 < m) {
        const float sc = alphap[0] * rp[(size_t)row * 4 + e] + 1.0f;
        const float4 lb = ((const float4*)l2b)[tid];
        o4.x = v.x + sc * lb.x; o4.y = v.y + sc * lb.y;
        o4.z = v.z + sc * lb.z; o4.w = v.w + sc * lb.w;
    } else {
        o4 = v;
    }
    ((float4*)(out + (size_t)row * DD))[tid] = o4;
}

// ---------------- OLD 128x128 GEMM1 (kept for e=2,3: K=256,128) ----------------
__global__ __launch_bounds__(256) void gemm1(
    const u16* __restrict__ h, const u16* __restrict__ w1b,
    const float* __restrict__ l1b, u16* __restrict__ inner,
    int K, int e)
{
    __shared__ __align__(16) u16 lA[128 * 64];
    __shared__ __align__(16) u16 lB[128 * 64];
    const int tid  = threadIdx.x;
    const int lane = tid & 63;
    const int w    = tid >> 6;
    const int wr   = w >> 1, wc = w & 1;
    const int bm = blockIdx.y, bn = blockIdx.x;

    f32x4 acc[4][4] = {};

    const int srow = (lane >> 3);
    const int soff = ((lane & 7) ^ srow) * 8;

    for (int kt = 0; kt < K; kt += 64) {
#pragma unroll
        for (int i = 0; i < 4; ++i) {
            const int c   = w * 4 + i;
            const int row = c * 8 + srow;
            const int rl  = bm * 128 + row;
            const int g   = ((rl >> 10) << 12) + (e << 10) + (rl & 1023);
            async16(h + (size_t)g * DD + kt + soff, &lA[c * 512]);
        }
#pragma unroll
        for (int i = 0; i < 4; ++i) {
            const int c   = w * 4 + i;
            const int row = c * 8 + srow;
            async16(w1b + (size_t)(bn * 128 + row) * DD + kt + soff, &lB[c * 512]);
        }
        __syncthreads();
#pragma unroll
        for (int kk = 0; kk < 2; ++kk) {
            const int sg = ((kk * 4 + (lane >> 4)) ^ (lane & 7)) * 8;
            bf16x8 af[4], bq[4];
#pragma unroll
            for (int i = 0; i < 4; ++i)
                af[i] = *(const bf16x8*)&lA[(wr * 64 + i * 16 + (lane & 15)) * 64 + sg];
#pragma unroll
            for (int i = 0; i < 4; ++i)
                bq[i] = *(const bf16x8*)&lB[(wc * 64 + i * 16 + (lane & 15)) * 64 + sg];
#pragma unroll
            for (int mi = 0; mi < 4; ++mi)
#pragma unroll
                for (int ni = 0; ni < 4; ++ni)
                    acc[mi][ni] = __builtin_amdgcn_mfma_f32_16x16x32_bf16(
                        af[mi], bq[ni], acc[mi][ni], 0, 0, 0);
        }
        __syncthreads();
    }

    const int cbase = bn * 128 + wc * 64 + (lane & 15);
    const int rbase = bm * 128 + wr * 64 + (lane >> 4) * 4;
#pragma unroll
    for (int ni = 0; ni < 4; ++ni) {
        const int col = cbase + ni * 16;
        const float bias = l1b[col];
#pragma unroll
        for (int mi = 0; mi < 4; ++mi) {
            const int r0 = rbase + mi * 16;
#pragma unroll
            for (int r = 0; r < 4; ++r) {
                const float vv = acc[mi][ni][r] + bias;
                const float gg = 0.5f * vv * (1.0f + erff(vv * 0.7071067811865476f));
                inner[(size_t)(r0 + r) * NINNER + col] = f2bf(gg);
            }
        }
    }
}

// ---------------- OLD 128x128 GEMM2 (kept for e=3) ----------------
__global__ __launch_bounds__(256) void gemm2(
    const u16* __restrict__ inner, const u16* __restrict__ w2b,
    const float* __restrict__ rp, const float* __restrict__ alphap,
    float* __restrict__ out, int e, int lgBn, int lgCPB)
{
    __shared__ __align__(16) u16 lA[128 * 64];
    __shared__ __align__(16) u16 lB[128 * 64];
    const int tid  = threadIdx.x;
    const int lane = tid & 63;
    const int w    = tid >> 6;
    const int wr   = w >> 1, wc = w & 1;

    const int id    = blockIdx.x;
    const int xcd   = id & 7;
    const int j     = id >> 3;
    const int bm    = ((j >> lgCPB) << 3) | xcd;
    const int chunk = j & ((1 << lgCPB) - 1);
    const int bn    = chunk & ((1 << lgBn) - 1);
    const int s     = chunk >> lgBn;
    const int Kc    = NINNER >> (lgCPB - lgBn);
    const int k0    = s * Kc;

    f32x4 acc[4][4] = {};
    const int srow = (lane >> 3);
    const int soff = ((lane & 7) ^ srow) * 8;

    for (int kt = k0; kt < k0 + Kc; kt += 64) {
#pragma unroll
        for (int i = 0; i < 4; ++i) {
            const int c   = w * 4 + i;
            const int row = c * 8 + srow;
            async16(inner + (size_t)(bm * 128 + row) * NINNER + kt + soff, &lA[c * 512]);
        }
#pragma unroll
        for (int i = 0; i < 4; ++i) {
            const int c   = w * 4 + i;
            const int row = c * 8 + srow;
            async16(w2b + (size_t)(bn * 128 + row) * NINNER + kt + soff, &lB[c * 512]);
        }
        __syncthreads();
#pragma unroll
        for (int kk = 0; kk < 2; ++kk) {
            const int sg = ((kk * 4 + (lane >> 4)) ^ (lane & 7)) * 8;
            bf16x8 af[4], bq[4];
#pragma unroll
            for (int i = 0; i < 4; ++i)
                af[i] = *(const bf16x8*)&lA[(wr * 64 + i * 16 + (lane & 15)) * 64 + sg];
#pragma unroll
            for (int i = 0; i < 4; ++i)
                bq[i] = *(const bf16x8*)&lB[(wc * 64 + i * 16 + (lane & 15)) * 64 + sg];
#pragma unroll
            for (int mi = 0; mi < 4; ++mi)
#pragma unroll
                for (int ni = 0; ni < 4; ++ni)
                    acc[mi][ni] = __builtin_amdgcn_mfma_f32_16x16x32_bf16(
                        af[mi], bq[ni], acc[mi][ni], 0, 0, 0);
        }
        __syncthreads();
    }

    const float alpha = alphap[0];
    const int cbase = bn * 128 + wc * 64 + (lane & 15);
    const int rbase = bm * 128 + wr * 64 + (lane >> 4) * 4;
#pragma unroll
    for (int mi = 0; mi < 4; ++mi) {
#pragma unroll
        for (int r = 0; r < 4; ++r) {
            const int rl = rbase + mi * 16 + r;
            const int g  = ((rl >> 10) << 12) + (e << 10) + (rl & 1023);
            const float sc = alpha * rp[(size_t)g * 4 + e] + 1.0f;
#pragma unroll
            for (int ni = 0; ni < 4; ++ni) {
                const int col = cbase + ni * 16;
                unsafeAtomicAdd(out + (size_t)g * DD + col, sc * acc[mi][ni][r]);
            }
        }
    }
}

// ================= 256x256 8-wave 4-phase pipelined GEMMs =================
// BM=BN=256, BK=64, 512 thr (8 waves). Per K-tile: 4 phases = 4 C-quadrants
// (mh,nh) in order (0,0),(0,1),(1,0),(1,1). Within a quadrant each wave owns
// 64 rows (qr=w>>2) x 32 cols (qc=w&3) = 4x2 frags x 2 k-halves = 16 MFMA.
// Each phase issues ONE half-tile (128x64) prefetch for K-tile t+1 into the
// other LDS buffer; stage order A0,B0,B1,A1 matches first-use order.
// Counted vmcnt(4) at end of phases 1,2,4 (never 0 in loop): at each gate,
// the oldest 2 loads retired are exactly the half-tile read next phase.
// LDS: 2 dbuf x 2 halves x [128 rows x 64 u16, granule-XOR swizzled] per
// operand = 128 KiB -> 1 block/CU.

#define PH_PRE()  do { asm volatile("" ::: "memory");                        \
                       __builtin_amdgcn_s_barrier();                         \
                       asm volatile("s_waitcnt lgkmcnt(0)" ::: "memory");    \
                       __builtin_amdgcn_sched_barrier(0);                    \
                       __builtin_amdgcn_s_setprio(1); } while (0)
#define PH_POST(VM) do { __builtin_amdgcn_s_setprio(0);                      \
                       if (VM) { asm volatile("s_waitcnt vmcnt(4)" ::: "memory"); } \
                       else    { asm volatile("" ::: "memory"); }            \
                       __builtin_amdgcn_s_barrier(); } while (0)

__global__ __launch_bounds__(512, 2) void gemm1_big(
    const u16* __restrict__ h, const u16* __restrict__ w1b,
    const float* __restrict__ l1b, u16* __restrict__ inner,
    int K, int e)
{
    __shared__ __align__(16) u16 lA[2][2][8192];   // [buf][half][128*64]
    __shared__ __align__(16) u16 lB[2][2][8192];
    const int tid  = threadIdx.x;
    const int lane = tid & 63;
    const int w    = tid >> 6;          // 0..7
    const int qr   = w >> 2;            // 0..1
    const int qc   = w & 3;             // 0..3
    const int l15  = lane & 15, l4g = lane >> 4, l7 = lane & 7;
    const int lrow = lane >> 3;
    const int soff = ((lane & 7) ^ lrow) * 8;

    // XCD-chunked swizzle over 512 blocks (32 bm x 16 bn)
    const int id  = blockIdx.x;
    const int swz = (id & 7) * 64 + (id >> 3);
    const int bm  = swz >> 4, bn = swz & 15;

    const int NT = K >> 6;

    f32x4 acc[4][4][2] = {};
    bf16x8 af[4][2], bq[2][2];

    auto STAGE_A = [&](int buf, int half, int kt) {
        const int rbase = bm * 256 + half * 128;
#pragma unroll
        for (int i = 0; i < 2; ++i) {
            const int c  = i * 8 + w;
            const int rl = rbase + c * 8 + lrow;
            const int g  = ((rl >> 10) << 12) + (e << 10) + (rl & 1023);
            async16(h + (size_t)g * DD + kt + soff, &lA[buf][half][c * 512]);
        }
    };
    auto STAGE_B = [&](int buf, int half, int kt) {
        const int rbase = bn * 256 + half * 128;
#pragma unroll
        for (int i = 0; i < 2; ++i) {
            const int c   = i * 8 + w;
            const int row = rbase + c * 8 + lrow;
            async16(w1b + (size_t)row * DD + kt + soff, &lB[buf][half][c * 512]);
        }
    };
    auto DSA = [&](int buf, int half) {
#pragma unroll
        for (int mi = 0; mi < 4; ++mi)
#pragma unroll
            for (int kk = 0; kk < 2; ++kk)
                af[mi][kk] = *(const bf16x8*)&lA[buf][half]
                    [(qr * 64 + mi * 16 + l15) * 64 + ((kk * 4 + l4g) ^ l7) * 8];
    };
    auto DSB = [&](int buf, int half) {
#pragma unroll
        for (int ni = 0; ni < 2; ++ni)
#pragma unroll
            for (int kk = 0; kk < 2; ++kk)
                bq[ni][kk] = *(const bf16x8*)&lB[buf][half]
                    [(qc * 32 + ni * 16 + l15) * 64 + ((kk * 4 + l4g) ^ l7) * 8];
    };
    auto MM = [&](f32x4 (&ac)[4][2]) {
#pragma unroll
        for (int mi = 0; mi < 4; ++mi)
#pragma unroll
            for (int ni = 0; ni < 2; ++ni) {
                f32x4 c = ac[mi][ni];
                c = __builtin_amdgcn_mfma_f32_16x16x32_bf16(af[mi][0], bq[ni][0], c, 0, 0, 0);
                c = __builtin_amdgcn_mfma_f32_16x16x32_bf16(af[mi][1], bq[ni][1], c, 0, 0, 0);
                ac[mi][ni] = c;
            }
    };

    // prologue: K-tile 0 into buf0, order A0,B0,B1,A1; retire A0,B0
    STAGE_A(0, 0, 0); STAGE_B(0, 0, 0); STAGE_B(0, 1, 0); STAGE_A(0, 1, 0);
    asm volatile("s_waitcnt vmcnt(4)" ::: "memory");
    __builtin_amdgcn_s_barrier();

    for (int t = 0; t < NT; ++t) {
        const int cur = t & 1, nxt = cur ^ 1;
        const int kn  = (t + 1 < NT ? t + 1 : t) << 6;   // clamp: tail re-stages (dead buf)
        // ph1: quad (0,0)
        DSA(cur, 0); DSB(cur, 0);
        STAGE_A(nxt, 0, kn);
        PH_PRE();  MM(acc[0]);  PH_POST(1);
        // ph2: quad (0,1)  (af reused)
        DSB(cur, 1);
        STAGE_B(nxt, 0, kn);
        PH_PRE();  MM(acc[1]);  PH_POST(1);
        // ph3: quad (1,0)
        DSA(cur, 1); DSB(cur, 0);
        STAGE_B(nxt, 1, kn);
        PH_PRE();  MM(acc[2]);  PH_POST(0);
        // ph4: quad (1,1)
        DSB(cur, 1);
        STAGE_A(nxt, 1, kn);
        PH_PRE();  MM(acc[3]);  PH_POST(1);
    }

    // epilogue: bias + exact GELU -> bf16
#pragma unroll
    for (int nh = 0; nh < 2; ++nh) {
#pragma unroll
        for (int ni = 0; ni < 2; ++ni) {
            const int col  = bn * 256 + nh * 128 + qc * 32 + ni * 16 + l15;
            const float bias = l1b[col];
#pragma unroll
            for (int mh = 0; mh < 2; ++mh) {
                const int rb = bm * 256 + mh * 128 + qr * 64 + l4g * 4;
#pragma unroll
                for (int mi = 0; mi < 4; ++mi) {
#pragma unroll
                    for (int r = 0; r < 4; ++r) {
                        const float vv = acc[mh * 2 + nh][mi][ni][r] + bias;
                        const float gg = 0.5f * vv * (1.0f + erff(vv * 0.7071067811865476f));
                        inner[(size_t)(rb + mi * 16 + r) * NINNER + col] = f2bf(gg);
                    }
                }
            }
        }
    }
}

__global__ __launch_bounds__(512, 2) void gemm2_big(
    const u16* __restrict__ inner, const u16* __restrict__ w2b,
    const float* __restrict__ rp, const float* __restrict__ alphap,
    float* __restrict__ out, int e, int lgNBN)
{
    __shared__ __align__(16) u16 lA[2][2][8192];
    __shared__ __align__(16) u16 lB[2][2][8192];
    const int tid  = threadIdx.x;
    const int lane = tid & 63;
    const int w    = tid >> 6;
    const int qr   = w >> 2;
    const int qc   = w & 3;
    const int l15  = lane & 15, l4g = lane >> 4, l7 = lane & 7;
    const int lrow = lane >> 3;
    const int soff = ((lane & 7) ^ lrow) * 8;

    // grid 256 = 32 bm x 8 chunks; all 8 chunks of a bm share one XCD slot
    const int id    = blockIdx.x;
    const int xcd   = id & 7;
    const int j     = id >> 3;               // 0..31
    const int bm    = ((j >> 3) << 3) | xcd; // 0..31
    const int chunk = j & 7;
    const int bn    = chunk & ((1 << lgNBN) - 1);
    const int s     = chunk >> lgNBN;
    const int Kc    = NINNER >> (3 - lgNBN); // 2048 / 1024 / 512
    const int k0    = s * Kc;
    const int NT    = Kc >> 6;

    f32x4 acc[4][4][2] = {};
    bf16x8 af[4][2], bq[2][2];

    auto STAGE_A = [&](int buf, int half, int kt) {
        const int rbase = bm * 256 + half * 128;
#pragma unroll
        for (int i = 0; i < 2; ++i) {
            const int c   = i * 8 + w;
            const int row = rbase + c * 8 + lrow;
            async16(inner + (size_t)row * NINNER + kt + soff, &lA[buf][half][c * 512]);
        }
    };
    auto STAGE_B = [&](int buf, int half, int kt) {
        const int rbase = bn * 256 + half * 128;
#pragma unroll
        for (int i = 0; i < 2; ++i) {
            const int c   = i * 8 + w;
            const int row = rbase + c * 8 + lrow;
            async16(w2b + (size_t)row * NINNER + kt + soff, &lB[buf][half][c * 512]);
        }
    };
    auto DSA = [&](int buf, int half) {
#pragma unroll
        for (int mi = 0; mi < 4; ++mi)
#pragma unroll
            for (int kk = 0; kk < 2; ++kk)
                af[mi][kk] = *(const bf16x8*)&lA[buf][half]
                    [(qr * 64 + mi * 16 + l15) * 64 + ((kk * 4 + l4g) ^ l7) * 8];
    };
    auto DSB = [&](int buf, int half) {
#pragma unroll
        for (int ni = 0; ni < 2; ++ni)
#pragma unroll
            for (int kk = 0; kk < 2; ++kk)
                bq[ni][kk] = *(const bf16x8*)&lB[buf][half]
                    [(qc * 32 + ni * 16 + l15) * 64 + ((kk * 4 + l4g) ^ l7) * 8];
    };
    auto MM = [&](f32x4 (&ac)[4][2]) {
#pragma unroll
        for (int mi = 0; mi < 4; ++mi)
#pragma unroll
            for (int ni = 0; ni < 2; ++ni) {
                f32x4 c = ac[mi][ni];
                c = __builtin_amdgcn_mfma_f32_16x16x32_bf16(af[mi][0], bq[ni][0], c, 0, 0, 0);
                c = __builtin_amdgcn_mfma_f32_16x16x32_bf16(af[mi][1], bq[ni][1], c, 0, 0, 0);
                ac[mi][ni] = c;
            }
    };

    STAGE_A(0, 0, k0); STAGE_B(0, 0, k0); STAGE_B(0, 1, k0); STAGE_A(0, 1, k0);
    asm volatile("s_waitcnt vmcnt(4)" ::: "memory");
    __builtin_amdgcn_s_barrier();

    for (int t = 0; t < NT; ++t) {
        const int cur = t & 1, nxt = cur ^ 1;
        const int kn  = k0 + ((t + 1 < NT ? t + 1 : t) << 6);
        DSA(cur, 0); DSB(cur, 0);
        STAGE_A(nxt, 0, kn);
        PH_PRE();  MM(acc[0]);  PH_POST(1);
        DSB(cur, 1);
        STAGE_B(nxt, 0, kn);
        PH_PRE();  MM(acc[1]);  PH_POST(1);
        DSA(cur, 1); DSB(cur, 0);
        STAGE_B(nxt, 1, kn);
        PH_PRE();  MM(acc[2]);  PH_POST(0);
        DSB(cur, 1);
        STAGE_A(nxt, 1, kn);
        PH_PRE();  MM(acc[3]);  PH_POST(1);
    }

    const float alpha = alphap[0];
#pragma unroll
    for (int mh = 0; mh < 2; ++mh) {
        const int rb = bm * 256 + mh * 128 + qr * 64 + l4g * 4;
#pragma unroll
        for (int mi = 0; mi < 4; ++mi) {
#pragma unroll
            for (int r = 0; r < 4; ++r) {
                const int rl = rb + mi * 16 + r;
                const int g  = ((rl >> 10) << 12) + (e << 10) + (rl & 1023);
                const float sc = alpha * rp[(size_t)g * 4 + e] + 1.0f;
#pragma unroll
                for (int nh = 0; nh < 2; ++nh) {
#pragma unroll
                    for (int ni = 0; ni < 2; ++ni) {
                        const int col = bn * 256 + nh * 128 + qc * 32 + ni * 16 + l15;
                        unsafeAtomicAdd(out + (size_t)g * DD + col,
                                        sc * acc[mh * 2 + nh][mi][ni][r]);
                    }
                }
            }
        }
    }
}

extern "C" void kernel_launch(void* const* d_in, const int* in_sizes, int n_in,
                              void* d_out, int out_size, void* d_ws, size_t ws_size,
                              hipStream_t stream) {
    const float* x     = (const float*)d_in[0];
    const float* rp    = (const float*)d_in[1];
    const float* alpha = (const float*)d_in[2];
    const float* nw    = (const float*)d_in[3];
    const float* nb    = (const float*)d_in[4];
    const float* l1w   = (const float*)d_in[5];
    const float* l1b   = (const float*)d_in[6];
    const float* l2w   = (const float*)d_in[7];
    const float* l2b   = (const float*)d_in[8];
    float* out = (float*)d_out;

    // workspace layout: h (64MB) | inner (64MB) | w1b (8MB) | w2b (8MB)
    char* ws = (char*)d_ws;
    if (ws_size < ((size_t)144 << 20)) return;
    u16* h     = (u16*)(ws);
    u16* inner = (u16*)(ws + ((size_t)64 << 20));
    u16* w1b   = (u16*)(ws + ((size_t)128 << 20));
    u16* w2b   = (u16*)(ws + ((size_t)136 << 20));

    cast_w<<<8192, 256, 0, stream>>>(l1w, l2w, w1b, w2b);
    ln_kernel<<<NTOK, 256, 0, stream>>>(x, nw, nb, l2b, rp, alpha, h, out);
    for (int e = 0; e < 4; ++e) {
        const int m = DD >> e;
        if (e < 2)
            gemm1_big<<<512, 512, 0, stream>>>(h, w1b, l1b, inner, m, e);
        else
            gemm1<<<dim3(NINNER / 128, MROWS / 128), 256, 0, stream>>>(h, w1b, l1b, inner, m, e);
        if (e < 3)
            gemm2_big<<<256, 512, 0, stream>>>(inner, w2b, rp, alpha, out, e, 2 - e);
        else
            gemm2<<<64 << 3, 256, 0, stream>>>(inner, w2b, rp, alpha, out, e, 0, 3);
    }
}